// Round 7
// baseline (470.396 us; speedup 1.0000x reference)
//
#include <hip/hip_runtime.h>

// M=512, N=2048, B=4, L=20, H density 0.02 (row weight ~41, col weight ~10).
// FULLY FUSED single kernel: preprocessing (row build / slice CSC / weight
// gather) + 20-layer BP, one dispatch. Rationale: R0-R6 consistently show
// ~200-237us of non-main dispatches (launch overhead + serial single-block
// kernels); the preprocessing work itself is ~30us of traffic.
// Main loop is byte-identical to R6 (column-partitioned, coherent-pp exchange,
// flush-free per-layer barrier).
#define MM 512
#define NN 2048
#define BB 4
#define LL 20
#define MAXDEG 128      // per-row cap (~13 sigma)
#define NT    1024
#define NBLK  32        // BB*RR blocks, all resident (<=256 CUs)
#define RR    8         // column slices per batch
#define COLSB 256       // NN / RR columns per slice
#define SLOTS 4096      // padded edge slots per slice (~2621 expected, +29 sigma)
#define EPSV  1e-6f

// ---------------- workspace layout (bytes) ----------------
#define WS_ROW_DEG   0          // int[512]
#define WS_ROW_PAD   2048       // int[512*128]
#define WS_ROW_OFFF  264192     // float[512]
#define WS_RPTR_RB   266240     // int[RR*513] (pad to 282880)
#define WS_EDGE_CS   282880     // uint[RR*SLOTS] (row<<16|col), slice-major, row-sorted
#define WS_WDE_P     413952     // float[L*RR*SLOTS]  per-slice padded, 16B-aligned segs
#define WS_MWDE_P    3035392    // float[L*RR*SLOTS]
#define WS_PP        5656832    // float[2*B*RR*512] row-product partials (parity dbuf)
#define WS_BAR       5787904    // int[B*64] per-batch layer counters + int[64] pre counters
// total ~5.79 MB

// ---- global barrier across ALL 32 blocks (preprocessing only, 3 uses) ----
// Round-0-proven pattern: release __threadfence (L2 writeback to MALL) before
// the counter, acquire __threadfence after. Full L2 flush is fine at 3x/launch
// (it was only harmful at 20x/block/layer -> R5 removed it from the hot loop).
// FAILSAFE: bounded spin -> wrong answer instead of container kill.
__device__ __forceinline__ void pre_barrier(int* ctr) {
    __syncthreads();
    if (threadIdx.x == 0) {
        __threadfence();
        __hip_atomic_fetch_add(ctr, 1, __ATOMIC_RELAXED, __HIP_MEMORY_SCOPE_AGENT);
        int it = 0;
        while (__hip_atomic_load(ctr, __ATOMIC_RELAXED, __HIP_MEMORY_SCOPE_AGENT) < NBLK) {
            __builtin_amdgcn_s_sleep(1);
            if (++it > (1 << 22)) break;     // bounded failsafe
        }
        __threadfence();
    }
    __syncthreads();
}

// ---- per-batch barrier across RR blocks (hot loop, flush-free) ----
// Exchanged data (pp) uses agent-scope RELAXED atomic load/store (coherent at
// the MALL, cross-XCD valid) -> no cache flush, weights stay L2-resident (R5 win).
// Release: __syncthreads drains vmcnt(0) per wave before s_barrier; tid0
// waitcnt covers its own ops. Acquire: control dep + trailing __syncthreads.
__device__ __forceinline__ void grid_barrier(int* ctr) {
    __syncthreads();
    if (threadIdx.x == 0) {
        asm volatile("s_waitcnt vmcnt(0)" ::: "memory");
        __hip_atomic_fetch_add(ctr, 1, __ATOMIC_RELAXED, __HIP_MEMORY_SCOPE_AGENT);
        int it = 0;
        while (__hip_atomic_load(ctr, __ATOMIC_RELAXED, __HIP_MEMORY_SCOPE_AGENT) < RR) {
            __builtin_amdgcn_s_sleep(1);
            if (++it > (1 << 22)) break;     // bounded failsafe
        }
        asm volatile("" ::: "memory");
    }
    __syncthreads();
}

// ---- fused kernel: 32 blocks = 4 batches x 8 COLUMN-slices ----
__global__ __launch_bounds__(NT, 4)
void nbp_all(const int* __restrict__ synd, const int* __restrict__ errs,
             const float* __restrict__ H, const float* __restrict__ llrs,
             const float* __restrict__ w_de, const float* __restrict__ w_llr,
             const float* __restrict__ mw_de, const float* __restrict__ mw_llr,
             const float* __restrict__ rhos, const float* __restrict__ resw,
             int* __restrict__ row_deg, int* __restrict__ row_pad,
             float* __restrict__ row_offf, int* __restrict__ rptr_rb,
             unsigned* __restrict__ edge_cs,
             float* __restrict__ wde_p, float* __restrict__ mwde_p,
             float* __restrict__ pp, int* __restrict__ bar,
             float* __restrict__ out) {
    __shared__ float d_sb[SLOTS];          // 16 KB block-local d
    __shared__ int   tmp_s[MM];            // P2 scan scratch
    __shared__ float colsum_s[COLSB];      // owned columns: full colsum (local)
    __shared__ float bel_s[COLSB];         // belief accum (local)
    __shared__ float ncs_s[COLSB];         // next-layer colsum accum (local)
    __shared__ float llrs_s[COLSB];
    __shared__ float ef_s[COLSB];          // 1 - error
    __shared__ float rowprod_s[MM];        // full row products after combine
    __shared__ float rp_coef[MM];          // row_offf * (-1)^syndrome
    __shared__ int   rowptr_s[MM + 1];     // block-local row segment offsets
    __shared__ float rho_n[LL];
    __shared__ float red[16];
    // ~30 KB total

    const int blk = blockIdx.x;
    const int b = blk & 3, r = blk >> 2;   // batch, column-slice
    const int tid = threadIdx.x;
    const int lane = tid & 63, wave = tid >> 6;
    int* bar_b = bar + b * 64;
    int* pbar  = bar + BB * 64;            // global preprocessing counters

    // ================= P1: build rows (512 waves = 1 wave/row) =================
    {
        int i = blk * 16 + wave;           // this wave's row
        const float* hrow = H + (size_t)i * NN;
        int base = 0;
        for (int pass = 0; pass < 4; ++pass) {
            float v[8];
            #pragma unroll
            for (int c = 0; c < 8; ++c) v[c] = hrow[(pass * 8 + c) * 64 + lane];
            #pragma unroll
            for (int c = 0; c < 8; ++c) {
                bool pred = v[c] != 0.0f;
                unsigned long long mask = __ballot(pred);
                int before = __popcll(mask & ((1ull << lane) - 1ull));
                if (pred) {
                    int k = base + before;
                    if (k < MAXDEG) row_pad[i * MAXDEG + k] = (pass * 8 + c) * 64 + lane;
                }
                base += __popcll(mask);
            }
        }
        if (lane == 0) {
            row_deg[i] = base < MAXDEG ? base : MAXDEG;
            // off-support entries contribute clip(1.0)=1-eps each to the row product
            row_offf[i] = powf(1.0f - EPSV, (float)(NN - base));
        }
    }
    pre_barrier(&pbar[0]);

    // ============ P2: per-slice count/scan/fill (blocks 0..7, slice=blk) ============
    if (blk < RR) {
        const int slice = blk;
        if (tid < MM) {
            int deg = row_deg[tid], cnt = 0;
            for (int k = 0; k < deg; ++k)
                cnt += ((row_pad[tid * MAXDEG + k] >> 8) == slice);
            tmp_s[tid] = cnt;
        }
        __syncthreads();
        for (int off = 1; off < MM; off <<= 1) {       // inclusive Hillis-Steele
            int v = (tid < MM && tid >= off) ? tmp_s[tid - off] : 0;
            __syncthreads();
            if (tid < MM) tmp_s[tid] += v;
            __syncthreads();
        }
        if (tid == 0) rptr_rb[slice * 513] = 0;
        if (tid < MM) rptr_rb[slice * 513 + tid + 1] = tmp_s[tid];
        __syncthreads();
        if (tid < MM) {
            int deg = row_deg[tid];
            int pos = (tid == 0) ? 0 : tmp_s[tid - 1];  // exclusive base for this row
            for (int k = 0; k < deg; ++k) {
                int c = row_pad[tid * MAXDEG + k];
                if ((c >> 8) == slice && pos < SLOTS) {
                    edge_cs[slice * SLOTS + pos] = ((unsigned)tid << 16) | (unsigned)c;
                    ++pos;
                }
            }
        }
    }
    pre_barrier(&pbar[1]);

    // ====== P3: gather weights (slice r, layers b*5..b*5+4 per block) ======
    {
        int tot = rptr_rb[r * 513 + MM];
        if (tot > SLOTS) tot = SLOTS;
        for (int l = b * 5; l < b * 5 + 5; ++l) {
            for (int s = tid; s < SLOTS; s += NT) {
                size_t di = ((size_t)(l * RR + r)) * SLOTS + s;
                if (s < tot) {
                    unsigned pk = edge_cs[r * SLOTS + s];
                    size_t src = (size_t)l * MM * NN + (size_t)(pk >> 16) * NN + (pk & 0xffffu);
                    wde_p[di]  = w_de[src];
                    mwde_p[di] = mw_de[src];
                } else {
                    wde_p[di]  = 0.0f;     // padded slots: defined zeros
                    mwde_p[di] = 0.0f;
                }
            }
        }
    }
    pre_barrier(&pbar[2]);

    // ================= main 20-layer loop (identical to R6) =================
    if (tid == 0) {
        float mx = -1e30f;
        for (int l = 0; l < LL; ++l) mx = fmaxf(mx, rhos[l]);
        float s = 0.0f;
        for (int l = 0; l < LL; ++l) { float e = __expf(rhos[l] - mx); rho_n[l] = e; s += e; }
        for (int l = 0; l < LL; ++l) rho_n[l] /= s;
    }
    if (tid < MM) {
        rowptr_s[tid] = rptr_rb[r * 513 + tid];
        rp_coef[tid] = row_offf[tid] * (1.0f - 2.0f * (float)synd[b * MM + tid]);
    }
    if (tid == MM) rowptr_s[MM] = rptr_rb[r * 513 + MM];
    if (tid < COLSB) {
        int j = r * COLSB + tid;
        float lj = llrs[j];
        llrs_s[tid] = lj;
        colsum_s[tid] = lj * w_llr[j];     // layer-0 colsum: msgs are zero
        ef_s[tid] = 1.0f - (float)errs[b * NN + j];
        bel_s[tid] = 0.0f;
        ncs_s[tid] = 0.0f;
    }

    int cnt = rptr_rb[r * 513 + MM];
    if (cnt > SLOTS) cnt = SLOTS;
    const int s0 = 4 * tid;                // this thread's first local slot

    // per-thread contiguous edge state (slice-major, row-sorted)
    unsigned idx[4];
    float msg[4], d_r[4];
    #pragma unroll
    for (int k = 0; k < 4; ++k) {
        int e = r * SLOTS + s0 + k;
        idx[k] = edge_cs[(s0 + k) < cnt ? e : r * SLOTS];   // clone first edge
        msg[k] = 0.0f;
    }
    __syncthreads();

    float loss = 0.0f;

    for (int l = 0; l < LL; ++l) {
        const float rw = resw[l];
        const int par = l & 1;
        float* pp_b = pp + ((size_t)par * BB + b) * RR * MM;

        // ---- B: prefetch weights (aligned float4) + per-edge tanh ----
        const float4 mq = *(const float4*)(mwde_p + ((size_t)(l * RR + r) * SLOTS) + s0);
        float4 wq = make_float4(0.f, 0.f, 0.f, 0.f);
        if (l + 1 < LL)
            wq = *(const float4*)(wde_p + ((size_t)((l + 1) * RR + r) * SLOTS) + s0);
        const float mv[4] = {mq.x, mq.y, mq.z, mq.w};
        const float wn[4] = {wq.x, wq.y, wq.z, wq.w};

        #pragma unroll
        for (int k = 0; k < 4; ++k) {
            int jl = idx[k] & 255u;                           // local col (slice-aligned)
            float en = colsum_s[jl] - msg[k];
            float t = __expf(en);                             // tanh(en/2)=1-2/(e^en+1)
            float d = 1.0f - 2.0f * __builtin_amdgcn_rcpf(t + 1.0f);
            if (d == 0.0f) d = 1.0f;                          // ref: where(d==0,1,d)
            d = fminf(fmaxf(d, -1.0f + EPSV), 1.0f - EPSV);
            d_r[k] = d;
        }
        *(float4*)&d_sb[s0] = make_float4(d_r[0], d_r[1], d_r[2], d_r[3]);
        __syncthreads();

        // ---- C: per-row PARTIAL products (in-slice deg ~5) -> coherent store ----
        if (tid < MM) {
            int lo = rowptr_s[tid], hi = rowptr_s[tid + 1];
            if (hi > SLOTS) hi = SLOTS;
            float p = 1.0f;
            for (int s = lo; s < hi; ++s) p *= d_sb[s];
            __hip_atomic_store(&pp_b[r * MM + tid], p,
                               __ATOMIC_RELAXED, __HIP_MEMORY_SCOPE_AGENT);
        }
        grid_barrier(&bar_b[l]);

        // ---- combine: full row product = rp_coef * prod of 8 partials ----
        if (tid < MM) {
            float p = rp_coef[tid];
            #pragma unroll
            for (int r2 = 0; r2 < RR; ++r2)
                p *= __hip_atomic_load(&pp_b[r2 * MM + tid],
                                       __ATOMIC_RELAXED, __HIP_MEMORY_SCOPE_AGENT);
            rowprod_s[tid] = p;
        }
        __syncthreads();

        // ---- D: atanh + msg update + LOCAL scatter (bel + next colsum) ----
        #pragma unroll
        for (int k = 0; k < 4; ++k) {
            int il = idx[k] >> 16;
            int jl = idx[k] & 255u;
            float rq = rowprod_s[il] * __builtin_amdgcn_rcpf(d_r[k]);
            // sgn*2*atanh(x) = 2*atanh(sgn*x); sgn folded into rp_coef
            float v = __logf(1.0f + rq) - __logf(1.0f - rq) + rw * msg[k];
            msg[k] = v;
            if (s0 + k < cnt) {
                atomicAdd(&bel_s[jl], v * mv[k]);
                if (l + 1 < LL) atomicAdd(&ncs_s[jl], v * wn[k]);
            }
        }
        __syncthreads();

        // ---- E: loss + next colsum on OWNED 256 columns (all local) ----
        if (tid < COLSB) {
            int j = r * COLSB + tid;
            float bel = llrs_s[tid] * mw_llr[l * NN + j] + bel_s[tid];
            bel_s[tid] = 0.0f;
            float sp = fmaxf(bel, 0.0f) + log1pf(__expf(-fabsf(bel)));  // softplus
            loss += rho_n[l] * (sp - ef_s[tid] * bel);
            if (l + 1 < LL) {
                colsum_s[tid] = llrs_s[tid] * w_llr[(l + 1) * NN + j] + ncs_s[tid];
                ncs_s[tid] = 0.0f;
            }
        }
        __syncthreads();
        // pp parity double-buffer: straggler combining layer l reads pp[par]
        // while others write pp[par^1] at C(l+1); layer l+2's reuse of pp[par]
        // is fenced by barrier(l+1). Safe.
    }

    // ---- block reduction of loss, then one global atomic ----
    #pragma unroll
    for (int off = 32; off > 0; off >>= 1) loss += __shfl_down(loss, off);
    if (lane == 0) red[wave] = loss;
    __syncthreads();
    if (wave == 0) {
        float v = (lane < 16) ? red[lane] : 0.0f;
        #pragma unroll
        for (int off = 8; off > 0; off >>= 1) v += __shfl_down(v, off);
        if (lane == 0) atomicAdd(out, v * 0.25f);
    }
}

extern "C" void kernel_launch(void* const* d_in, const int* in_sizes, int n_in,
                              void* d_out, int out_size, void* d_ws, size_t ws_size,
                              hipStream_t stream) {
    const int*   synd  = (const int*)  d_in[0];
    const int*   errs  = (const int*)  d_in[1];
    const float* H     = (const float*)d_in[2];
    const float* llrs  = (const float*)d_in[3];
    const float* w_de  = (const float*)d_in[4];
    const float* w_llr = (const float*)d_in[5];
    const float* mw_de = (const float*)d_in[6];
    const float* mw_llr= (const float*)d_in[7];
    const float* rhos  = (const float*)d_in[8];
    const float* resw  = (const float*)d_in[9];

    char* ws = (char*)d_ws;
    int*      row_deg  = (int*)     (ws + WS_ROW_DEG);
    int*      row_pad  = (int*)     (ws + WS_ROW_PAD);
    float*    row_offf = (float*)   (ws + WS_ROW_OFFF);
    int*      rptr_rb  = (int*)     (ws + WS_RPTR_RB);
    unsigned* edge_cs  = (unsigned*)(ws + WS_EDGE_CS);
    float*    wde_p    = (float*)   (ws + WS_WDE_P);
    float*    mwde_p   = (float*)   (ws + WS_MWDE_P);
    float*    pp       = (float*)   (ws + WS_PP);
    int*      bar      = (int*)     (ws + WS_BAR);
    float*    out      = (float*)d_out;

    hipMemsetAsync(bar, 0, (BB * 64 + 64) * sizeof(int), stream);
    hipMemsetAsync(d_out, 0, sizeof(float), stream);

    nbp_all<<<NBLK, NT, 0, stream>>>(synd, errs, H, llrs, w_de, w_llr, mw_de, mw_llr,
                                     rhos, resw, row_deg, row_pad, row_offf, rptr_rb,
                                     edge_cs, wde_p, mwde_p, pp, bar, out);
}

// Round 8
// 439.455 us; speedup vs baseline: 1.0704x; 1.0704x over previous
//
#include <hip/hip_runtime.h>

// M=512, N=2048, B=4, L=20, H density 0.02 (row weight ~41, col weight ~10).
// Single fused kernel, 64 blocks = 4 batches x 16 column-slices.
// vs R7: (1) NO weight pre-gather -- per-layer scattered loads straight from
// dense w_de/mw_de, issued early, hidden under the barrier-bound layer chain
// (R7's in-kernel gather on 32 CUs cost ~100us); (2) RR 8->16 doubles
// parallelism (R6 showed per-layer time ~2/3 compute+skew); (3) d_out memset
// replaced by in-kernel self-zero (one fewer dispatch, ~17us/dispatch measured).
#define MM 512
#define NN 2048
#define BB 4
#define LL 20
#define MAXDEG 128      // per-row cap (~13 sigma)
#define NT    1024
#define RR    16        // column slices per batch
#define NBLK  64        // BB*RR blocks, all resident
#define COLSB 128       // NN / RR columns per slice
#define SLOTS 2048      // padded edge slots per slice (~1310 expected, +20 sigma)
#define EPT   2         // edges per thread
#define EPSV  1e-6f

// ---------------- workspace layout (bytes) ----------------
#define WS_ROW_DEG   0          // int[512]
#define WS_ROW_PAD   2048       // int[512*128]
#define WS_ROW_OFFF  264192     // float[512]
#define WS_RPTR_RB   266240     // int[RR*513]
#define WS_EDGE_CS   299072     // uint[RR*SLOTS] (row<<16|col), slice-major, row-sorted
#define WS_PP        430144     // float[2*B*RR*512] row-product partials (parity dbuf)
#define WS_BAR       692288     // int[B*64] per-batch layer counters + int[64] pre counters
// total ~0.68 MB

// ---- global barrier across ALL 64 blocks (preprocessing only, 2 uses) ----
// __threadfence release/acquire (L2 wb + inv) is fine at 2x/launch; it was only
// harmful at 20x/block/layer (R5). FAILSAFE: bounded spin.
__device__ __forceinline__ void pre_barrier(int* ctr) {
    __syncthreads();
    if (threadIdx.x == 0) {
        __threadfence();
        __hip_atomic_fetch_add(ctr, 1, __ATOMIC_RELAXED, __HIP_MEMORY_SCOPE_AGENT);
        int it = 0;
        while (__hip_atomic_load(ctr, __ATOMIC_RELAXED, __HIP_MEMORY_SCOPE_AGENT) < NBLK) {
            __builtin_amdgcn_s_sleep(1);
            if (++it > (1 << 22)) break;     // bounded failsafe
        }
        __threadfence();
    }
    __syncthreads();
}

// ---- per-batch barrier across RR blocks (hot loop, flush-free) ----
// pp uses agent-scope RELAXED atomic load/store (coherent at the MALL) -> no
// cache flush, weights stay L2-resident (R5 win). Release: __syncthreads drains
// vmcnt(0) before s_barrier; tid0 waitcnt covers its own ops. Acquire: control
// dep + trailing __syncthreads. Fresh counter per layer (memset each launch).
__device__ __forceinline__ void grid_barrier(int* ctr) {
    __syncthreads();
    if (threadIdx.x == 0) {
        asm volatile("s_waitcnt vmcnt(0)" ::: "memory");
        __hip_atomic_fetch_add(ctr, 1, __ATOMIC_RELAXED, __HIP_MEMORY_SCOPE_AGENT);
        int it = 0;
        while (__hip_atomic_load(ctr, __ATOMIC_RELAXED, __HIP_MEMORY_SCOPE_AGENT) < RR) {
            __builtin_amdgcn_s_sleep(1);
            if (++it > (1 << 22)) break;     // bounded failsafe
        }
        asm volatile("" ::: "memory");
    }
    __syncthreads();
}

// ---- fused kernel: 64 blocks = 4 batches x 16 COLUMN-slices ----
__global__ __launch_bounds__(NT)
void nbp_all(const int* __restrict__ synd, const int* __restrict__ errs,
             const float* __restrict__ H, const float* __restrict__ llrs,
             const float* __restrict__ w_de, const float* __restrict__ w_llr,
             const float* __restrict__ mw_de, const float* __restrict__ mw_llr,
             const float* __restrict__ rhos, const float* __restrict__ resw,
             int* __restrict__ row_deg, int* __restrict__ row_pad,
             float* __restrict__ row_offf, int* __restrict__ rptr_rb,
             unsigned* __restrict__ edge_cs,
             float* __restrict__ pp, int* __restrict__ bar,
             float* __restrict__ out) {
    __shared__ float d_sb[SLOTS];          // 8 KB block-local d
    __shared__ int   tmp_s[MM];            // P2 scan scratch
    __shared__ float colsum_s[COLSB];      // owned columns: full colsum (local)
    __shared__ float bel_s[COLSB];         // belief accum (local)
    __shared__ float ncs_s[COLSB];         // next-layer colsum accum (local)
    __shared__ float llrs_s[COLSB];
    __shared__ float ef_s[COLSB];          // 1 - error
    __shared__ float rowprod_s[MM];        // full row products after combine
    __shared__ float rp_coef[MM];          // row_offf * (-1)^syndrome
    __shared__ int   rowptr_s[MM + 1];     // block-local row segment offsets
    __shared__ float rho_n[LL];
    __shared__ float red[16];
    // ~19 KB total

    const int blk = blockIdx.x;
    const int b = blk & 3, r = blk >> 2;   // batch, column-slice
    const int tid = threadIdx.x;
    const int lane = tid & 63, wave = tid >> 6;
    int* bar_b = bar + b * 64;
    int* pbar  = bar + BB * 64;            // global preprocessing counters

    // self-zero the output (replaces a memset dispatch); ordered before all
    // final atomicAdds by pre_barrier(0)'s fences.
    if (blk == 0 && tid == 0)
        __hip_atomic_store(out, 0.0f, __ATOMIC_RELAXED, __HIP_MEMORY_SCOPE_AGENT);

    // ================= P1: build rows (512 waves = 1 wave/row) =================
    if (wave < 8) {
        int i = blk * 8 + wave;            // this wave's row
        const float* hrow = H + (size_t)i * NN;
        int base = 0;
        for (int pass = 0; pass < 4; ++pass) {
            float v[8];
            #pragma unroll
            for (int c = 0; c < 8; ++c) v[c] = hrow[(pass * 8 + c) * 64 + lane];
            #pragma unroll
            for (int c = 0; c < 8; ++c) {
                bool pred = v[c] != 0.0f;
                unsigned long long mask = __ballot(pred);
                int before = __popcll(mask & ((1ull << lane) - 1ull));
                if (pred) {
                    int k = base + before;
                    if (k < MAXDEG) row_pad[i * MAXDEG + k] = (pass * 8 + c) * 64 + lane;
                }
                base += __popcll(mask);
            }
        }
        if (lane == 0) {
            row_deg[i] = base < MAXDEG ? base : MAXDEG;
            // off-support entries contribute clip(1.0)=1-eps each to the row product
            row_offf[i] = powf(1.0f - EPSV, (float)(NN - base));
        }
    }
    pre_barrier(&pbar[0]);

    // ======== P2: per-slice count/scan/fill (blocks 0..15, slice=blk) ========
    if (blk < RR) {
        const int slice = blk;
        if (tid < MM) {
            int deg = row_deg[tid], cnt = 0;
            for (int k = 0; k < deg; ++k)
                cnt += ((row_pad[tid * MAXDEG + k] >> 7) == slice);   // slice=col/128
            tmp_s[tid] = cnt;
        }
        __syncthreads();
        for (int off = 1; off < MM; off <<= 1) {       // inclusive Hillis-Steele
            int v = (tid < MM && tid >= off) ? tmp_s[tid - off] : 0;
            __syncthreads();
            if (tid < MM) tmp_s[tid] += v;
            __syncthreads();
        }
        if (tid == 0) rptr_rb[slice * 513] = 0;
        if (tid < MM) rptr_rb[slice * 513 + tid + 1] = tmp_s[tid];
        __syncthreads();
        if (tid < MM) {
            int deg = row_deg[tid];
            int pos = (tid == 0) ? 0 : tmp_s[tid - 1];  // exclusive base for this row
            for (int k = 0; k < deg; ++k) {
                int c = row_pad[tid * MAXDEG + k];
                if ((c >> 7) == slice && pos < SLOTS) {
                    edge_cs[slice * SLOTS + pos] = ((unsigned)tid << 16) | (unsigned)c;
                    ++pos;
                }
            }
        }
    }
    pre_barrier(&pbar[1]);

    // ================= main 20-layer loop =================
    if (tid == 0) {
        float mx = -1e30f;
        for (int l = 0; l < LL; ++l) mx = fmaxf(mx, rhos[l]);
        float s = 0.0f;
        for (int l = 0; l < LL; ++l) { float e = __expf(rhos[l] - mx); rho_n[l] = e; s += e; }
        for (int l = 0; l < LL; ++l) rho_n[l] /= s;
    }
    if (tid < MM) {
        rowptr_s[tid] = rptr_rb[r * 513 + tid];
        rp_coef[tid] = row_offf[tid] * (1.0f - 2.0f * (float)synd[b * MM + tid]);
    }
    if (tid == MM) rowptr_s[MM] = rptr_rb[r * 513 + MM];
    if (tid < COLSB) {
        int j = r * COLSB + tid;
        float lj = llrs[j];
        llrs_s[tid] = lj;
        colsum_s[tid] = lj * w_llr[j];     // layer-0 colsum: msgs are zero
        ef_s[tid] = 1.0f - (float)errs[b * NN + j];
        bel_s[tid] = 0.0f;
        ncs_s[tid] = 0.0f;
    }

    int cnt = rptr_rb[r * 513 + MM];
    if (cnt > SLOTS) cnt = SLOTS;
    const int s0 = EPT * tid;              // this thread's first local slot

    // per-thread contiguous edge state (slice-major, row-sorted)
    unsigned idx[EPT];
    float msg[EPT], d_r[EPT];
    #pragma unroll
    for (int k = 0; k < EPT; ++k) {
        int e = r * SLOTS + s0 + k;
        idx[k] = edge_cs[(s0 + k) < cnt ? e : r * SLOTS];   // clone first edge
        msg[k] = 0.0f;
    }
    __syncthreads();

    float loss = 0.0f;

    for (int l = 0; l < LL; ++l) {
        const float rw = resw[l];
        const int par = l & 1;
        float* pp_b = pp + ((size_t)par * BB + b) * RR * MM;

        // ---- issue scattered weight loads EARLY (consumed in D; they hide
        // under B+C and the grid barrier, which is the per-layer floor) ----
        float mv[EPT], wn[EPT];
        {
            const float* mwl = mw_de + (size_t)l * (MM * NN);
            const float* wl  = w_de + (size_t)(l + 1) * (MM * NN);
            #pragma unroll
            for (int k = 0; k < EPT; ++k) {
                size_t eo = (size_t)(idx[k] >> 16) * NN + (idx[k] & 0xffffu);
                mv[k] = mwl[eo];
                wn[k] = (l + 1 < LL) ? wl[eo] : 0.0f;
            }
        }

        // ---- B: per-edge tanh (d) ----
        #pragma unroll
        for (int k = 0; k < EPT; ++k) {
            int jl = idx[k] & (COLSB - 1);                    // local col (slice-aligned)
            float en = colsum_s[jl] - msg[k];
            float t = __expf(en);                             // tanh(en/2)=1-2/(e^en+1)
            float d = 1.0f - 2.0f * __builtin_amdgcn_rcpf(t + 1.0f);
            if (d == 0.0f) d = 1.0f;                          // ref: where(d==0,1,d)
            d = fminf(fmaxf(d, -1.0f + EPSV), 1.0f - EPSV);
            d_r[k] = d;
        }
        *(float2*)&d_sb[s0] = make_float2(d_r[0], d_r[1]);
        __syncthreads();

        // ---- C: per-row PARTIAL products (in-slice deg ~2.6) -> coherent store ----
        if (tid < MM) {
            int lo = rowptr_s[tid], hi = rowptr_s[tid + 1];
            if (hi > SLOTS) hi = SLOTS;
            float p = 1.0f;
            for (int s = lo; s < hi; ++s) p *= d_sb[s];
            __hip_atomic_store(&pp_b[r * MM + tid], p,
                               __ATOMIC_RELAXED, __HIP_MEMORY_SCOPE_AGENT);
        }
        grid_barrier(&bar_b[l]);

        // ---- combine: full row product = rp_coef * prod of 16 partials ----
        if (tid < MM) {
            float p = rp_coef[tid];
            #pragma unroll
            for (int r2 = 0; r2 < RR; ++r2)
                p *= __hip_atomic_load(&pp_b[r2 * MM + tid],
                                       __ATOMIC_RELAXED, __HIP_MEMORY_SCOPE_AGENT);
            rowprod_s[tid] = p;
        }
        __syncthreads();

        // ---- D: atanh + msg update + LOCAL scatter (bel + next colsum) ----
        #pragma unroll
        for (int k = 0; k < EPT; ++k) {
            int il = idx[k] >> 16;
            int jl = idx[k] & (COLSB - 1);
            float rq = rowprod_s[il] * __builtin_amdgcn_rcpf(d_r[k]);
            // sgn*2*atanh(x) = 2*atanh(sgn*x); sgn folded into rp_coef
            float v = __logf(1.0f + rq) - __logf(1.0f - rq) + rw * msg[k];
            msg[k] = v;
            if (s0 + k < cnt) {
                atomicAdd(&bel_s[jl], v * mv[k]);
                if (l + 1 < LL) atomicAdd(&ncs_s[jl], v * wn[k]);
            }
        }
        __syncthreads();

        // ---- E: loss + next colsum on OWNED 128 columns (all local) ----
        if (tid < COLSB) {
            int j = r * COLSB + tid;
            float bel = llrs_s[tid] * mw_llr[l * NN + j] + bel_s[tid];
            bel_s[tid] = 0.0f;
            float sp = fmaxf(bel, 0.0f) + log1pf(__expf(-fabsf(bel)));  // softplus
            loss += rho_n[l] * (sp - ef_s[tid] * bel);
            if (l + 1 < LL) {
                colsum_s[tid] = llrs_s[tid] * w_llr[(l + 1) * NN + j] + ncs_s[tid];
                ncs_s[tid] = 0.0f;
            }
        }
        __syncthreads();
        // pp parity double-buffer: straggler combining layer l reads pp[par]
        // while others write pp[par^1] at C(l+1); layer l+2's reuse of pp[par]
        // is fenced by barrier(l+1). Safe.
    }

    // ---- block reduction of loss, then one global atomic ----
    #pragma unroll
    for (int off = 32; off > 0; off >>= 1) loss += __shfl_down(loss, off);
    if (lane == 0) red[wave] = loss;
    __syncthreads();
    if (wave == 0) {
        float v = (lane < 16) ? red[lane] : 0.0f;
        #pragma unroll
        for (int off = 8; off > 0; off >>= 1) v += __shfl_down(v, off);
        if (lane == 0) atomicAdd(out, v * 0.25f);
    }
}

extern "C" void kernel_launch(void* const* d_in, const int* in_sizes, int n_in,
                              void* d_out, int out_size, void* d_ws, size_t ws_size,
                              hipStream_t stream) {
    const int*   synd  = (const int*)  d_in[0];
    const int*   errs  = (const int*)  d_in[1];
    const float* H     = (const float*)d_in[2];
    const float* llrs  = (const float*)d_in[3];
    const float* w_de  = (const float*)d_in[4];
    const float* w_llr = (const float*)d_in[5];
    const float* mw_de = (const float*)d_in[6];
    const float* mw_llr= (const float*)d_in[7];
    const float* rhos  = (const float*)d_in[8];
    const float* resw  = (const float*)d_in[9];

    char* ws = (char*)d_ws;
    int*      row_deg  = (int*)     (ws + WS_ROW_DEG);
    int*      row_pad  = (int*)     (ws + WS_ROW_PAD);
    float*    row_offf = (float*)   (ws + WS_ROW_OFFF);
    int*      rptr_rb  = (int*)     (ws + WS_RPTR_RB);
    unsigned* edge_cs  = (unsigned*)(ws + WS_EDGE_CS);
    float*    pp       = (float*)   (ws + WS_PP);
    int*      bar      = (int*)     (ws + WS_BAR);
    float*    out      = (float*)d_out;

    hipMemsetAsync(bar, 0, (BB * 64 + 64) * sizeof(int), stream);

    nbp_all<<<NBLK, NT, 0, stream>>>(synd, errs, H, llrs, w_de, w_llr, mw_de, mw_llr,
                                     rhos, resw, row_deg, row_pad, row_offf, rptr_rb,
                                     edge_cs, pp, bar, out);
}

// Round 9
// 395.303 us; speedup vs baseline: 1.1900x; 1.1117x over previous
//
#include <hip/hip_runtime.h>

// M=512, N=2048, B=4, L=20, H density 0.02 (row weight ~41, col weight ~10).
// Single fused kernel, 64 blocks = 4 batches x 16 column-slices.
// vs R8: (1) weight path reverted to COMPACT PRE-GATHER (R8's per-layer
// scattered loads put 159MB on HBM and ~3.5us/layer on the critical path);
// gather now runs fused, distributed over all 64 blocks x 320 (l,slice) pairs;
// (2) combine uses 2 threads/row (8 loads each + shfl merge) halving the
// serial coherent-load chain.
#define MM 512
#define NN 2048
#define BB 4
#define LL 20
#define MAXDEG 128      // per-row cap (~13 sigma)
#define NT    1024
#define RR    16        // column slices per batch
#define NBLK  64        // BB*RR blocks, all resident
#define COLSB 128       // NN / RR columns per slice
#define SLOTS 2048      // padded edge slots per slice (~1310 expected, +20 sigma)
#define EPT   2         // edges per thread
#define EPSV  1e-6f

// ---------------- workspace layout (bytes) ----------------
#define WS_ROW_DEG   0          // int[512]
#define WS_ROW_PAD   2048       // int[512*128]
#define WS_ROW_OFFF  264192     // float[512]
#define WS_RPTR_RB   266240     // int[RR*513]
#define WS_EDGE_CS   299072     // uint[RR*SLOTS] (row<<16|col), slice-major, row-sorted
#define WS_WDE_P     430144     // float[L*RR*SLOTS] compact per-slice segments
#define WS_MWDE_P    3051584    // float[L*RR*SLOTS]
#define WS_PP        5673024    // float[2*B*RR*512] row-product partials (parity dbuf)
#define WS_BAR       5935168    // int[B*64] layer counters + int[64] pre counters
// total ~5.94 MB

// ---- global barrier across ALL 64 blocks (preprocessing only, 3 uses) ----
// __threadfence release/acquire (L2 wb + inv at the MALL) is fine at 3x/launch;
// it was only harmful at 20x/block/layer (R5). After this fence, plain cached
// loads of data written by other XCDs are safe. FAILSAFE: bounded spin.
__device__ __forceinline__ void pre_barrier(int* ctr) {
    __syncthreads();
    if (threadIdx.x == 0) {
        __threadfence();
        __hip_atomic_fetch_add(ctr, 1, __ATOMIC_RELAXED, __HIP_MEMORY_SCOPE_AGENT);
        int it = 0;
        while (__hip_atomic_load(ctr, __ATOMIC_RELAXED, __HIP_MEMORY_SCOPE_AGENT) < NBLK) {
            __builtin_amdgcn_s_sleep(1);
            if (++it > (1 << 22)) break;     // bounded failsafe
        }
        __threadfence();
    }
    __syncthreads();
}

// ---- per-batch barrier across RR blocks (hot loop, flush-free) ----
// pp uses agent-scope RELAXED atomic load/store (coherent at the MALL) -> no
// cache flush, weights stay L2-resident (R5 win). Release: __syncthreads drains
// vmcnt(0) before s_barrier; tid0 waitcnt covers its own ops. Acquire: control
// dep + trailing __syncthreads. Fresh counter per layer (memset each launch).
__device__ __forceinline__ void grid_barrier(int* ctr) {
    __syncthreads();
    if (threadIdx.x == 0) {
        asm volatile("s_waitcnt vmcnt(0)" ::: "memory");
        __hip_atomic_fetch_add(ctr, 1, __ATOMIC_RELAXED, __HIP_MEMORY_SCOPE_AGENT);
        int it = 0;
        while (__hip_atomic_load(ctr, __ATOMIC_RELAXED, __HIP_MEMORY_SCOPE_AGENT) < RR) {
            __builtin_amdgcn_s_sleep(1);
            if (++it > (1 << 22)) break;     // bounded failsafe
        }
        asm volatile("" ::: "memory");
    }
    __syncthreads();
}

// ---- fused kernel: 64 blocks = 4 batches x 16 COLUMN-slices ----
__global__ __launch_bounds__(NT)
void nbp_all(const int* __restrict__ synd, const int* __restrict__ errs,
             const float* __restrict__ H, const float* __restrict__ llrs,
             const float* __restrict__ w_de, const float* __restrict__ w_llr,
             const float* __restrict__ mw_de, const float* __restrict__ mw_llr,
             const float* __restrict__ rhos, const float* __restrict__ resw,
             int* __restrict__ row_deg, int* __restrict__ row_pad,
             float* __restrict__ row_offf, int* __restrict__ rptr_rb,
             unsigned* __restrict__ edge_cs,
             float* __restrict__ wde_p, float* __restrict__ mwde_p,
             float* __restrict__ pp, int* __restrict__ bar,
             float* __restrict__ out) {
    __shared__ float d_sb[SLOTS];          // 8 KB block-local d
    __shared__ int   tmp_s[MM];            // P2 scan scratch
    __shared__ float colsum_s[COLSB];      // owned columns: full colsum (local)
    __shared__ float bel_s[COLSB];         // belief accum (local)
    __shared__ float ncs_s[COLSB];         // next-layer colsum accum (local)
    __shared__ float llrs_s[COLSB];
    __shared__ float ef_s[COLSB];          // 1 - error
    __shared__ float rowprod_s[MM];        // full row products after combine
    __shared__ float rp_coef[MM];          // row_offf * (-1)^syndrome
    __shared__ int   rowptr_s[MM + 1];     // block-local row segment offsets
    __shared__ float rho_n[LL];
    __shared__ float red[16];
    // ~19 KB total

    const int blk = blockIdx.x;
    const int b = blk & 3, r = blk >> 2;   // batch, column-slice
    const int tid = threadIdx.x;
    const int lane = tid & 63, wave = tid >> 6;
    int* bar_b = bar + b * 64;
    int* pbar  = bar + BB * 64;            // global preprocessing counters

    // self-zero the output (replaces a memset dispatch); ordered before all
    // final atomicAdds by pre_barrier(0)'s fences.
    if (blk == 0 && tid == 0)
        __hip_atomic_store(out, 0.0f, __ATOMIC_RELAXED, __HIP_MEMORY_SCOPE_AGENT);

    // ================= P1: build rows (512 waves = 1 wave/row) =================
    if (wave < 8) {
        int i = blk * 8 + wave;            // this wave's row
        const float* hrow = H + (size_t)i * NN;
        int base = 0;
        for (int pass = 0; pass < 4; ++pass) {
            float v[8];
            #pragma unroll
            for (int c = 0; c < 8; ++c) v[c] = hrow[(pass * 8 + c) * 64 + lane];
            #pragma unroll
            for (int c = 0; c < 8; ++c) {
                bool pred = v[c] != 0.0f;
                unsigned long long mask = __ballot(pred);
                int before = __popcll(mask & ((1ull << lane) - 1ull));
                if (pred) {
                    int k = base + before;
                    if (k < MAXDEG) row_pad[i * MAXDEG + k] = (pass * 8 + c) * 64 + lane;
                }
                base += __popcll(mask);
            }
        }
        if (lane == 0) {
            row_deg[i] = base < MAXDEG ? base : MAXDEG;
            // off-support entries contribute clip(1.0)=1-eps each to the row product
            row_offf[i] = powf(1.0f - EPSV, (float)(NN - base));
        }
    }
    pre_barrier(&pbar[0]);

    // ======== P2: per-slice count/scan/fill (blocks 0..15, slice=blk) ========
    if (blk < RR) {
        const int slice = blk;
        if (tid < MM) {
            int deg = row_deg[tid], cnt = 0;
            for (int k = 0; k < deg; ++k)
                cnt += ((row_pad[tid * MAXDEG + k] >> 7) == slice);   // slice=col/128
            tmp_s[tid] = cnt;
        }
        __syncthreads();
        for (int off = 1; off < MM; off <<= 1) {       // inclusive Hillis-Steele
            int v = (tid < MM && tid >= off) ? tmp_s[tid - off] : 0;
            __syncthreads();
            if (tid < MM) tmp_s[tid] += v;
            __syncthreads();
        }
        if (tid == 0) rptr_rb[slice * 513] = 0;
        if (tid < MM) rptr_rb[slice * 513 + tid + 1] = tmp_s[tid];
        __syncthreads();
        if (tid < MM) {
            int deg = row_deg[tid];
            int pos = (tid == 0) ? 0 : tmp_s[tid - 1];  // exclusive base for this row
            for (int k = 0; k < deg; ++k) {
                int c = row_pad[tid * MAXDEG + k];
                if ((c >> 7) == slice && pos < SLOTS) {
                    edge_cs[slice * SLOTS + pos] = ((unsigned)tid << 16) | (unsigned)c;
                    ++pos;
                }
            }
        }
    }
    pre_barrier(&pbar[1]);

    // ==== P3: compact weight gather, 320 (l,slice) pairs over 64 blocks ====
    // ~2.6 scattered loads/thread/pair -> latency well covered by 16 waves.
    for (int pr = blk; pr < LL * RR; pr += NBLK) {
        int l = pr / RR, slc = pr - l * RR;
        int tot = rptr_rb[slc * 513 + MM];
        if (tot > SLOTS) tot = SLOTS;
        const float* wl  = w_de + (size_t)l * (MM * NN);
        const float* mwl = mw_de + (size_t)l * (MM * NN);
        for (int s = tid; s < SLOTS; s += NT) {
            size_t di = (size_t)pr * SLOTS + s;
            if (s < tot) {
                unsigned pk = edge_cs[slc * SLOTS + s];
                size_t eo = (size_t)(pk >> 16) * NN + (pk & 0xffffu);
                wde_p[di]  = wl[eo];
                mwde_p[di] = mwl[eo];
            } else {
                wde_p[di]  = 0.0f;         // padded slots: defined zeros
                mwde_p[di] = 0.0f;
            }
        }
    }
    pre_barrier(&pbar[2]);

    // ================= main 20-layer loop =================
    if (tid == 0) {
        float mx = -1e30f;
        for (int l = 0; l < LL; ++l) mx = fmaxf(mx, rhos[l]);
        float s = 0.0f;
        for (int l = 0; l < LL; ++l) { float e = __expf(rhos[l] - mx); rho_n[l] = e; s += e; }
        for (int l = 0; l < LL; ++l) rho_n[l] /= s;
    }
    if (tid < MM) {
        rowptr_s[tid] = rptr_rb[r * 513 + tid];
        rp_coef[tid] = row_offf[tid] * (1.0f - 2.0f * (float)synd[b * MM + tid]);
    }
    if (tid == MM) rowptr_s[MM] = rptr_rb[r * 513 + MM];
    if (tid < COLSB) {
        int j = r * COLSB + tid;
        float lj = llrs[j];
        llrs_s[tid] = lj;
        colsum_s[tid] = lj * w_llr[j];     // layer-0 colsum: msgs are zero
        ef_s[tid] = 1.0f - (float)errs[b * NN + j];
        bel_s[tid] = 0.0f;
        ncs_s[tid] = 0.0f;
    }

    int cnt = rptr_rb[r * 513 + MM];
    if (cnt > SLOTS) cnt = SLOTS;
    const int s0 = EPT * tid;              // this thread's first local slot

    // per-thread contiguous edge state (slice-major, row-sorted)
    unsigned idx[EPT];
    float msg[EPT], d_r[EPT];
    #pragma unroll
    for (int k = 0; k < EPT; ++k) {
        int e = r * SLOTS + s0 + k;
        idx[k] = edge_cs[(s0 + k) < cnt ? e : r * SLOTS];   // clone first edge
        msg[k] = 0.0f;
    }
    __syncthreads();

    float loss = 0.0f;

    for (int l = 0; l < LL; ++l) {
        const float rw = resw[l];
        const int par = l & 1;
        float* pp_b = pp + ((size_t)par * BB + b) * RR * MM;

        // ---- compact weight loads (aligned float2), issued early; they hide
        // under B+C+barrier. L2-resident after the P3 full-fence barrier. ----
        const float2 mq = *(const float2*)(mwde_p + ((size_t)(l * RR + r) * SLOTS) + s0);
        float2 wq = make_float2(0.f, 0.f);
        if (l + 1 < LL)
            wq = *(const float2*)(wde_p + ((size_t)((l + 1) * RR + r) * SLOTS) + s0);
        const float mv[2] = {mq.x, mq.y};
        const float wn[2] = {wq.x, wq.y};

        // ---- B: per-edge tanh (d) ----
        #pragma unroll
        for (int k = 0; k < EPT; ++k) {
            int jl = idx[k] & (COLSB - 1);                    // local col (slice-aligned)
            float en = colsum_s[jl] - msg[k];
            float t = __expf(en);                             // tanh(en/2)=1-2/(e^en+1)
            float d = 1.0f - 2.0f * __builtin_amdgcn_rcpf(t + 1.0f);
            if (d == 0.0f) d = 1.0f;                          // ref: where(d==0,1,d)
            d = fminf(fmaxf(d, -1.0f + EPSV), 1.0f - EPSV);
            d_r[k] = d;
        }
        *(float2*)&d_sb[s0] = make_float2(d_r[0], d_r[1]);
        __syncthreads();

        // ---- C: per-row PARTIAL products (in-slice deg ~2.6) -> coherent store ----
        if (tid < MM) {
            int lo = rowptr_s[tid], hi = rowptr_s[tid + 1];
            if (hi > SLOTS) hi = SLOTS;
            float p = 1.0f;
            for (int s = lo; s < hi; ++s) p *= d_sb[s];
            __hip_atomic_store(&pp_b[r * MM + tid], p,
                               __ATOMIC_RELAXED, __HIP_MEMORY_SCOPE_AGENT);
        }
        grid_barrier(&bar_b[l]);

        // ---- combine: 2 threads/row, 8 coherent loads each + shfl merge ----
        {
            int row = tid >> 1, half = tid & 1;
            float p = 1.0f;
            #pragma unroll
            for (int q = 0; q < RR / 2; ++q) {
                int r2 = q * 2 + half;
                p *= __hip_atomic_load(&pp_b[r2 * MM + row],
                                       __ATOMIC_RELAXED, __HIP_MEMORY_SCOPE_AGENT);
            }
            p *= __shfl_xor(p, 1);         // tid pairs are lane-adjacent
            if (half == 0) rowprod_s[row] = p * rp_coef[row];
        }
        __syncthreads();

        // ---- D: atanh + msg update + LOCAL scatter (bel + next colsum) ----
        #pragma unroll
        for (int k = 0; k < EPT; ++k) {
            int il = idx[k] >> 16;
            int jl = idx[k] & (COLSB - 1);
            float rq = rowprod_s[il] * __builtin_amdgcn_rcpf(d_r[k]);
            // sgn*2*atanh(x) = 2*atanh(sgn*x); sgn folded into rp_coef
            float v = __logf(1.0f + rq) - __logf(1.0f - rq) + rw * msg[k];
            msg[k] = v;
            if (s0 + k < cnt) {
                atomicAdd(&bel_s[jl], v * mv[k]);
                if (l + 1 < LL) atomicAdd(&ncs_s[jl], v * wn[k]);
            }
        }
        __syncthreads();

        // ---- E: loss + next colsum on OWNED 128 columns (all local) ----
        if (tid < COLSB) {
            int j = r * COLSB + tid;
            float bel = llrs_s[tid] * mw_llr[l * NN + j] + bel_s[tid];
            bel_s[tid] = 0.0f;
            float sp = fmaxf(bel, 0.0f) + log1pf(__expf(-fabsf(bel)));  // softplus
            loss += rho_n[l] * (sp - ef_s[tid] * bel);
            if (l + 1 < LL) {
                colsum_s[tid] = llrs_s[tid] * w_llr[(l + 1) * NN + j] + ncs_s[tid];
                ncs_s[tid] = 0.0f;
            }
        }
        __syncthreads();
        // pp parity double-buffer: straggler combining layer l reads pp[par]
        // while others write pp[par^1] at C(l+1); layer l+2's reuse of pp[par]
        // is fenced by barrier(l+1). Safe.
    }

    // ---- block reduction of loss, then one global atomic ----
    #pragma unroll
    for (int off = 32; off > 0; off >>= 1) loss += __shfl_down(loss, off);
    if (lane == 0) red[wave] = loss;
    __syncthreads();
    if (wave == 0) {
        float v = (lane < 16) ? red[lane] : 0.0f;
        #pragma unroll
        for (int off = 8; off > 0; off >>= 1) v += __shfl_down(v, off);
        if (lane == 0) atomicAdd(out, v * 0.25f);
    }
}

extern "C" void kernel_launch(void* const* d_in, const int* in_sizes, int n_in,
                              void* d_out, int out_size, void* d_ws, size_t ws_size,
                              hipStream_t stream) {
    const int*   synd  = (const int*)  d_in[0];
    const int*   errs  = (const int*)  d_in[1];
    const float* H     = (const float*)d_in[2];
    const float* llrs  = (const float*)d_in[3];
    const float* w_de  = (const float*)d_in[4];
    const float* w_llr = (const float*)d_in[5];
    const float* mw_de = (const float*)d_in[6];
    const float* mw_llr= (const float*)d_in[7];
    const float* rhos  = (const float*)d_in[8];
    const float* resw  = (const float*)d_in[9];

    char* ws = (char*)d_ws;
    int*      row_deg  = (int*)     (ws + WS_ROW_DEG);
    int*      row_pad  = (int*)     (ws + WS_ROW_PAD);
    float*    row_offf = (float*)   (ws + WS_ROW_OFFF);
    int*      rptr_rb  = (int*)     (ws + WS_RPTR_RB);
    unsigned* edge_cs  = (unsigned*)(ws + WS_EDGE_CS);
    float*    wde_p    = (float*)   (ws + WS_WDE_P);
    float*    mwde_p   = (float*)   (ws + WS_MWDE_P);
    float*    pp       = (float*)   (ws + WS_PP);
    int*      bar      = (int*)     (ws + WS_BAR);
    float*    out      = (float*)d_out;

    hipMemsetAsync(bar, 0, (BB * 64 + 64) * sizeof(int), stream);

    nbp_all<<<NBLK, NT, 0, stream>>>(synd, errs, H, llrs, w_de, w_llr, mw_de, mw_llr,
                                     rhos, resw, row_deg, row_pad, row_offf, rptr_rb,
                                     edge_cs, wde_p, mwde_p, pp, bar, out);
}